// Round 6
// baseline (4979.094 us; speedup 1.0000x reference)
//
#include <hip/hip_runtime.h>

typedef unsigned short u16;
typedef unsigned int u32;
typedef short bf16x8 __attribute__((ext_vector_type(8)));
typedef float f32x4 __attribute__((ext_vector_type(4)));
typedef unsigned short u16x4 __attribute__((ext_vector_type(4)));

// ---------- bf16 helpers (RNE) ----------
__device__ __forceinline__ u16 f2bf(float f) {
    u32 u = __float_as_uint(f);
    u32 r = (u + 0x7FFFu + ((u >> 16) & 1u)) >> 16;
    return (u16)r;
}
__device__ __forceinline__ float bf2f(u16 h) { return __uint_as_float(((u32)h) << 16); }

// ---------- global -> LDS direct ----------
__device__ __forceinline__ void gll16(const void* g, void* l) {
    auto gp = reinterpret_cast<const __attribute__((address_space(1))) u32*>(
        reinterpret_cast<uintptr_t>(g));
    auto lp = reinterpret_cast<__attribute__((address_space(3))) u32*>(
        reinterpret_cast<uintptr_t>(l));
    __builtin_amdgcn_global_load_lds(gp, lp, 16, 0, 0);
}

// ---------- sentinel fill (diagnoses ws-too-small) ----------
__global__ void fill_f32(float* __restrict__ p, float v, int n) {
    int i = blockIdx.x * 256 + threadIdx.x;
    if (i < n) p[i] = v;
}

// ---------- split fp32 -> (hi,lo) bf16, optional 1/sigma scale ----------
__device__ __forceinline__ void split_body(const float* __restrict__ src, float sc,
                                           u16* __restrict__ hi, u16* __restrict__ lo, int i) {
    float4 f = reinterpret_cast<const float4*>(src)[i];
    float v0 = f.x * sc, v1 = f.y * sc, v2 = f.z * sc, v3 = f.w * sc;
    u16 h0 = f2bf(v0), h1 = f2bf(v1), h2 = f2bf(v2), h3 = f2bf(v3);
    u16x4 H = {h0, h1, h2, h3};
    u16x4 L = {f2bf(v0 - bf2f(h0)), f2bf(v1 - bf2f(h1)), f2bf(v2 - bf2f(h2)), f2bf(v3 - bf2f(h3))};
    reinterpret_cast<u16x4*>(hi)[i] = H;
    reinterpret_cast<u16x4*>(lo)[i] = L;
}

__global__ void split_hl(const float* __restrict__ src, const float* __restrict__ sigma,
                         u16* __restrict__ hi, u16* __restrict__ lo, int n4) {
    int i = blockIdx.x * 256 + threadIdx.x;
    if (i >= n4) return;
    float sc = sigma ? (1.0f / *sigma) : 1.0f;
    split_body(src, sc, hi, lo, i);
}

struct SJ { const float* src; u16* hi; u16* lo; };
struct SJ6 { SJ j[6]; };
__global__ void split_hl6(SJ6 jobs, int n4) {
    int i = blockIdx.x * 256 + threadIdx.x;
    if (i >= n4) return;
    const SJ J = jobs.j[blockIdx.y];
    split_body(J.src, 1.0f, J.hi, J.lo, i);
}

// ---------- spectral norm (tiny, deterministic) ----------
__global__ void sn_col(const float* __restrict__ W, const float* __restrict__ u,
                       int N, int K, float* __restrict__ vraw) {
    int j = blockIdx.x * 256 + threadIdx.x;
    if (j >= K) return;
    float acc = 0.f;
#pragma unroll 4
    for (int i = 0; i < N; ++i) acc = fmaf(W[(long)i * K + j], u[i], acc);
    vraw[j] = acc;
}

__global__ void sn_norm(const float* __restrict__ vraw, int K, float* __restrict__ vn) {
    const int t = threadIdx.x;
    float x = (t < K) ? vraw[t] : 0.f;
    float s = x * x;
#pragma unroll
    for (int o = 1; o < 64; o <<= 1) s += __shfl_xor(s, o);
    __shared__ float red[16];
    if ((t & 63) == 0) red[t >> 6] = s;
    __syncthreads();
    if (t == 0) {
        float S = 0.f;
        for (int i = 0; i < 16; ++i) S += red[i];
        red[0] = 1.0f / (sqrtf(S) + 1e-12f);
    }
    __syncthreads();
    if (t < K) vn[t] = x * red[0];
}

__global__ void sn_dot(const float* __restrict__ W, const float* __restrict__ vn,
                       const float* __restrict__ u, int N, int K, float* __restrict__ rowdot) {
    const int row = (blockIdx.x << 2) + (threadIdx.x >> 6);
    const int l = threadIdx.x & 63;
    const float* wr = W + (long)row * K;
    float s = 0.f;
    for (int j = l; j < K; j += 64) s = fmaf(wr[j], vn[j], s);
#pragma unroll
    for (int o = 1; o < 64; o <<= 1) s += __shfl_xor(s, o);
    if (l == 0) rowdot[row] = u[row] * s;
}

__global__ void sn_sig(const float* __restrict__ rd, int N, float* __restrict__ sig) {
    const int t = threadIdx.x;
    float x = (t < N) ? rd[t] : 0.f;
#pragma unroll
    for (int o = 1; o < 64; o <<= 1) x += __shfl_xor(x, o);
    __shared__ float red[16];
    if ((t & 63) == 0) red[t >> 6] = x;
    __syncthreads();
    if (t == 0) {
        float S = 0.f;
        for (int i = 0; i < 16; ++i) S += red[i];
        *sig = S;
    }
}

// ---------- hi/lo bf16 GEMM: C[m,n] = sum_k A[m,k]*B[n,k]  (NT) ----------
// EPI 0: write fp32 (+opt bias). EPI 1: write bf16 hi/lo (+opt bias).
template <int EPI>
__global__ __launch_bounds__(256, 2) void gemm_hl(
    const u16* __restrict__ Ah, const u16* __restrict__ Al, int lda,
    const u16* __restrict__ Bh, const u16* __restrict__ Bl, int ldb,
    int K, const float* __restrict__ bias,
    float* __restrict__ Cf, u16* __restrict__ Chi, u16* __restrict__ Clo, int ldc) {
    __shared__ u16 lds[16384];  // Ahi | Alo | Bhi | Blo, each [128][32] bf16 (8KB)
    const int tid = threadIdx.x;
    const int l = tid & 63;
    const int w = tid >> 6;
    const int m0 = blockIdx.x << 7;
    const int n0 = blockIdx.y << 7;

    const int srow = (w << 4) + (l >> 2);
    const int scol = (l & 3) << 3;
    const long offA0 = (long)(m0 + srow) * lda + scol;
    const long offA1 = offA0 + ((long)lda << 6);
    const long offB0 = (long)(n0 + srow) * ldb + scol;
    const long offB1 = offB0 + ((long)ldb << 6);
    char* lb = (char*)lds + (w << 10);

    f32x4 acc[4][4];
#pragma unroll
    for (int i = 0; i < 4; ++i)
#pragma unroll
        for (int j = 0; j < 4; ++j) acc[i][j] = (f32x4){0.f, 0.f, 0.f, 0.f};

    const int wm = (w >> 1) << 6;
    const int wn = (w & 1) << 6;
    const int fq = (l >> 4) << 3;
    const int fr = l & 15;

    for (int k0 = 0; k0 < K; k0 += 32) {
        __syncthreads();
        gll16(Ah + offA0 + k0, lb);
        gll16(Ah + offA1 + k0, lb + 4096);
        gll16(Al + offA0 + k0, lb + 8192);
        gll16(Al + offA1 + k0, lb + 12288);
        gll16(Bh + offB0 + k0, lb + 16384);
        gll16(Bh + offB1 + k0, lb + 20480);
        gll16(Bl + offB0 + k0, lb + 24576);
        gll16(Bl + offB1 + k0, lb + 28672);
        __syncthreads();

        bf16x8 a0[4], a1[4], b0[4], b1[4];
#pragma unroll
        for (int mi = 0; mi < 4; ++mi) {
            int r = wm + (mi << 4) + fr;
            a0[mi] = *(const bf16x8*)(lds + (r << 5) + fq);
            a1[mi] = *(const bf16x8*)(lds + 4096 + (r << 5) + fq);
        }
#pragma unroll
        for (int ni = 0; ni < 4; ++ni) {
            int r = wn + (ni << 4) + fr;
            b0[ni] = *(const bf16x8*)(lds + 8192 + (r << 5) + fq);
            b1[ni] = *(const bf16x8*)(lds + 12288 + (r << 5) + fq);
        }
#pragma unroll
        for (int mi = 0; mi < 4; ++mi)
#pragma unroll
            for (int ni = 0; ni < 4; ++ni) {
                acc[mi][ni] = __builtin_amdgcn_mfma_f32_16x16x32_bf16(a0[mi], b0[ni], acc[mi][ni], 0, 0, 0);
                acc[mi][ni] = __builtin_amdgcn_mfma_f32_16x16x32_bf16(a0[mi], b1[ni], acc[mi][ni], 0, 0, 0);
                acc[mi][ni] = __builtin_amdgcn_mfma_f32_16x16x32_bf16(a1[mi], b0[ni], acc[mi][ni], 0, 0, 0);
            }
    }

    const int r0 = (l >> 4) << 2;
#pragma unroll
    for (int mi = 0; mi < 4; ++mi) {
#pragma unroll
        for (int ni = 0; ni < 4; ++ni) {
            const int gc = n0 + wn + (ni << 4) + fr;
            const float bv = bias ? bias[gc] : 0.0f;
#pragma unroll
            for (int r = 0; r < 4; ++r) {
                const int gr = m0 + wm + (mi << 4) + r0 + r;
                float v = acc[mi][ni][r] + bv;
                if (EPI == 0) {
                    Cf[(long)gr * ldc + gc] = v;
                } else {
                    u16 h = f2bf(v);
                    Chi[(long)gr * ldc + gc] = h;
                    Clo[(long)gr * ldc + gc] = f2bf(v - bf2f(h));
                }
            }
        }
    }
}

// ---------- BatchNorm over channel s of [8][2048(s)][1024], on hi/lo planes ----------
__global__ void bn_stats_hl(const u16* __restrict__ hh, const u16* __restrict__ hl,
                            float* __restrict__ mean, float* __restrict__ rstd) {
    const int s = blockIdx.x, t = threadIdx.x;
    float sum = 0.f, sq = 0.f;
#pragma unroll
    for (int b = 0; b < 8; ++b) {
        long base = ((long)b * 2048 + s) * 1024 + (t << 2);
        u16x4 H = *(const u16x4*)(hh + base);
        u16x4 L = *(const u16x4*)(hl + base);
        float v0 = bf2f(H.x) + bf2f(L.x), v1 = bf2f(H.y) + bf2f(L.y);
        float v2 = bf2f(H.z) + bf2f(L.z), v3 = bf2f(H.w) + bf2f(L.w);
        sum += v0 + v1 + v2 + v3;
        sq += v0 * v0 + v1 * v1 + v2 * v2 + v3 * v3;
    }
#pragma unroll
    for (int o = 1; o < 64; o <<= 1) { sum += __shfl_xor(sum, o); sq += __shfl_xor(sq, o); }
    __shared__ float ss[4], qq[4];
    if ((t & 63) == 0) { ss[t >> 6] = sum; qq[t >> 6] = sq; }
    __syncthreads();
    if (t == 0) {
        float S = ss[0] + ss[1] + ss[2] + ss[3];
        float Q = qq[0] + qq[1] + qq[2] + qq[3];
        float m = S * (1.0f / 8192.0f);
        float var = Q * (1.0f / 8192.0f) - m * m;
        mean[s] = m;
        rstd[s] = rsqrtf(var + 1e-5f);
    }
}

__global__ void bn_apply_hl(u16* __restrict__ hh, u16* __restrict__ hl,
                            const float* __restrict__ mean, const float* __restrict__ rstd,
                            const float* __restrict__ g, const float* __restrict__ be) {
    const long i = ((long)blockIdx.x * 256 + threadIdx.x) << 2;
    const int s = (int)((i >> 10) & 2047);
    const float a = rstd[s] * g[s];
    const float c = fmaf(-mean[s], a, be[s]);
    u16x4 H = *(const u16x4*)(hh + i);
    u16x4 L = *(const u16x4*)(hl + i);
    float v0 = fmaf(bf2f(H.x) + bf2f(L.x), a, c);
    float v1 = fmaf(bf2f(H.y) + bf2f(L.y), a, c);
    float v2 = fmaf(bf2f(H.z) + bf2f(L.z), a, c);
    float v3 = fmaf(bf2f(H.w) + bf2f(L.w), a, c);
    v0 = v0 > 0.f ? v0 : 0.2f * v0;
    v1 = v1 > 0.f ? v1 : 0.2f * v1;
    v2 = v2 > 0.f ? v2 : 0.2f * v2;
    v3 = v3 > 0.f ? v3 : 0.2f * v3;
    u16 h0 = f2bf(v0), h1 = f2bf(v1), h2 = f2bf(v2), h3 = f2bf(v3);
    u16x4 HO = {h0, h1, h2, h3};
    u16x4 LO = {f2bf(v0 - bf2f(h0)), f2bf(v1 - bf2f(h1)), f2bf(v2 - bf2f(h2)), f2bf(v3 - bf2f(h3))};
    *(u16x4*)(hh + i) = HO;
    *(u16x4*)(hl + i) = LO;
}

// ---------- softmax over rows of 2048, in-place fp32 -> (hi,lo) bf16 ----------
__global__ __launch_bounds__(256) void softmax_hl(float* __restrict__ scores) {
    float* p = scores + ((long)blockIdx.x << 11);
    const int t = threadIdx.x;
    float4 f0 = *(const float4*)(p + (t << 2));
    float4 f1 = *(const float4*)(p + 1024 + (t << 2));
    float mx = fmaxf(fmaxf(fmaxf(f0.x, f0.y), fmaxf(f0.z, f0.w)),
                     fmaxf(fmaxf(f1.x, f1.y), fmaxf(f1.z, f1.w)));
#pragma unroll
    for (int o = 1; o < 64; o <<= 1) mx = fmaxf(mx, __shfl_xor(mx, o));
    __shared__ float red[4];
    if ((t & 63) == 0) red[t >> 6] = mx;
    __syncthreads();
    mx = fmaxf(fmaxf(red[0], red[1]), fmaxf(red[2], red[3]));
    float e0 = expf(f0.x - mx), e1 = expf(f0.y - mx), e2 = expf(f0.z - mx), e3 = expf(f0.w - mx);
    float e4 = expf(f1.x - mx), e5 = expf(f1.y - mx), e6 = expf(f1.z - mx), e7 = expf(f1.w - mx);
    float s = ((e0 + e1) + (e2 + e3)) + ((e4 + e5) + (e6 + e7));
#pragma unroll
    for (int o = 1; o < 64; o <<= 1) s += __shfl_xor(s, o);
    __syncthreads();
    if ((t & 63) == 0) red[t >> 6] = s;
    __syncthreads();
    const float inv = 1.0f / ((red[0] + red[1]) + (red[2] + red[3]));
    e0 *= inv; e1 *= inv; e2 *= inv; e3 *= inv; e4 *= inv; e5 *= inv; e6 *= inv; e7 *= inv;
    u16* hi = (u16*)p;
    u16* lo = hi + 2048;
    u16 h0 = f2bf(e0), h1 = f2bf(e1), h2 = f2bf(e2), h3 = f2bf(e3);
    u16 h4 = f2bf(e4), h5 = f2bf(e5), h6 = f2bf(e6), h7 = f2bf(e7);
    u16x4 H0 = {h0, h1, h2, h3}, H1 = {h4, h5, h6, h7};
    u16x4 L0 = {f2bf(e0 - bf2f(h0)), f2bf(e1 - bf2f(h1)), f2bf(e2 - bf2f(h2)), f2bf(e3 - bf2f(h3))};
    u16x4 L1 = {f2bf(e4 - bf2f(h4)), f2bf(e5 - bf2f(h5)), f2bf(e6 - bf2f(h6)), f2bf(e7 - bf2f(h7))};
    *(u16x4*)(hi + (t << 2)) = H0;
    *(u16x4*)(hi + 1024 + (t << 2)) = H1;
    *(u16x4*)(lo + (t << 2)) = L0;
    *(u16x4*)(lo + 1024 + (t << 2)) = L1;
}

// ---------- transpose [2048][1024] -> [1024][2048] (u16), both planes via z ----------
__global__ void transpose_hl2(const u16* __restrict__ src_hi, u16* __restrict__ dst_hi,
                              const u16* __restrict__ src_lo, u16* __restrict__ dst_lo) {
    __shared__ u16 tile[64][68];
    const u16* src = (blockIdx.z & 1) ? src_lo : src_hi;
    u16* dst = (blockIdx.z & 1) ? dst_lo : dst_hi;
    const int t0 = blockIdx.x << 6, d0 = blockIdx.y << 6;
    const int rr = threadIdx.x >> 4, cc = (threadIdx.x & 15) << 2;
#pragma unroll
    for (int it = 0; it < 4; ++it) {
        int r = (it << 4) + rr;
        u16x4 v = *(const u16x4*)(src + (long)(t0 + r) * 1024 + d0 + cc);
        tile[r][cc] = v.x; tile[r][cc + 1] = v.y; tile[r][cc + 2] = v.z; tile[r][cc + 3] = v.w;
    }
    __syncthreads();
#pragma unroll
    for (int it = 0; it < 4; ++it) {
        int r = (it << 4) + rr;
        u16x4 o;
        o.x = tile[cc][r]; o.y = tile[cc + 1][r]; o.z = tile[cc + 2][r]; o.w = tile[cc + 3][r];
        *(u16x4*)(dst + (long)(d0 + r) * 2048 + t0 + cc) = o;
    }
}

// ======================= host launcher =======================
extern "C" void kernel_launch(void* const* d_in, const int* in_sizes, int n_in,
                              void* d_out, int out_size, void* d_ws, size_t ws_size,
                              hipStream_t stream) {
    const float* x = (const float*)d_in[0];
    const float* W1 = (const float*)d_in[1];
    const float* b1 = (const float*)d_in[2];
    const float* u1 = (const float*)d_in[3];
    const float* g1 = (const float*)d_in[4];
    const float* be1 = (const float*)d_in[5];
    const float* Wq1 = (const float*)d_in[6];  const float* bq1 = (const float*)d_in[7];
    const float* Wk1 = (const float*)d_in[8];  const float* bk1 = (const float*)d_in[9];
    const float* Wv1 = (const float*)d_in[10]; const float* bv1 = (const float*)d_in[11];
    const float* W2 = (const float*)d_in[12];  const float* b2 = (const float*)d_in[13];
    const float* u2 = (const float*)d_in[14];
    const float* g2 = (const float*)d_in[15];  const float* be2 = (const float*)d_in[16];
    const float* Wq2 = (const float*)d_in[17]; const float* bq2 = (const float*)d_in[18];
    const float* Wk2 = (const float*)d_in[19]; const float* bk2 = (const float*)d_in[20];
    const float* Wv2 = (const float*)d_in[21]; const float* bv2 = (const float*)d_in[22];
    const float* W3 = (const float*)d_in[23];  const float* b3 = (const float*)d_in[24];
    const float* u3 = (const float*)d_in[25];

    // ---- workspace: ~160 MiB ----
    // R1 [67.1MB] | R2 [67.1MB] | WB [33.6MB] | smalls [32KB]
    // layer(X in, Y out, pool in X): lin X->Y; bn Y in-place; per batch b:
    //   qkv read Y[b] -> pool; attn -> o[b] overwrites Y[b] (h[b] dead).
    // layer1: X=R2 (x staged there), Y=R1. layer2: X=R1, Y=R2. final reads R2.
    const size_t NEED = 167804928ull;
    if (ws_size < NEED) {  // sentinel: next-round error==12345 <=> this tripped
        fill_f32<<<dim3((out_size + 255) / 256), 256, 0, stream>>>((float*)d_out, 12345.0f, out_size);
        return;
    }
    char* ws = (char*)d_ws;
    u16* R1h = (u16*)ws;                     u16* R1l = R1h + 16777216;
    u16* R2h = (u16*)(ws + 67108864);        u16* R2l = R2h + 16777216;
    u16* WBu = (u16*)(ws + 134217728);
    float* FS = (float*)(ws + 167772160);

    u16* W1h = WBu;                 u16* W1l = WBu + 524288;
    u16* Wq1h = WBu + 1048576;      u16* Wq1l = WBu + 2097152;
    u16* Wk1h = WBu + 3145728;      u16* Wk1l = WBu + 4194304;
    u16* Wv1h = WBu + 5242880;      u16* Wv1l = WBu + 6291456;
    u16* W2h = WBu + 7340032;       u16* W2l = WBu + 8388608;
    u16* Wq2h = WBu + 9437184;      u16* Wq2l = WBu + 10485760;
    u16* Wk2h = WBu + 11534336;     u16* Wk2l = WBu + 12582912;
    u16* Wv2h = WBu + 13631488;     u16* Wv2l = WBu + 14680064;
    u16* W3h = WBu + 15728640;      u16* W3l = WBu + 16252928;

    float* vraw = FS;        float* vn = FS + 1024;
    float* rowdot = FS + 2048;
    float* sig1 = FS + 3072; float* sig2 = FS + 3073; float* sig3 = FS + 3074;
    float* mean = FS + 4096; float* rstd = FS + 6144;

    auto split = [&](const float* src, const float* sg, u16* hi, u16* lo, int nElem) {
        split_hl<<<dim3(nElem / 1024), 256, 0, stream>>>(src, sg, hi, lo, nElem / 4);
    };
    auto spec = [&](const float* W, const float* u, int N, int Kd, float* sg) {
        sn_col<<<dim3(Kd / 256), 256, 0, stream>>>(W, u, N, Kd, vraw);
        sn_norm<<<dim3(1), 1024, 0, stream>>>(vraw, Kd, vn);
        sn_dot<<<dim3(N / 4), 256, 0, stream>>>(W, vn, u, N, Kd, rowdot);
        sn_sig<<<dim3(1), 1024, 0, stream>>>(rowdot, N, sg);
    };

    // ---- weight prep ----
    // x hi/lo staged in R2 (plane stride 8388608 u16; dead after lin1)
    u16* xh = R2h;  u16* xl = R2h + 8388608;
    split(x, nullptr, xh, xl, 8388608);
    spec(W1, u1, 1024, 512, sig1);  split(W1, sig1, W1h, W1l, 524288);
    spec(W2, u2, 1024, 1024, sig2); split(W2, sig2, W2h, W2l, 1048576);
    spec(W3, u3, 512, 1024, sig3);  split(W3, sig3, W3h, W3l, 524288);
    SJ6 sj;
    sj.j[0] = {Wq1, Wq1h, Wq1l};
    sj.j[1] = {Wk1, Wk1h, Wk1l};
    sj.j[2] = {Wv1, Wv1h, Wv1l};
    sj.j[3] = {Wq2, Wq2h, Wq2l};
    sj.j[4] = {Wk2, Wk2h, Wk2l};
    sj.j[5] = {Wv2, Wv2h, Wv2l};
    split_hl6<<<dim3(1024, 6), 256, 0, stream>>>(sj, 262144);

    // full layer: X=(inh,inl) input planes; Y=(Yh,Yl) h/o region; pool in P (byte base)
    auto full_layer = [&](const u16* inh, const u16* inl, int Kin,
                          u16* Yh, u16* Yl, char* P,
                          const u16* Wh, const u16* Wl, const float* bl,
                          const float* g, const float* be,
                          const u16* Wqh, const u16* Wql, const float* bq,
                          const u16* Wkh, const u16* Wkl, const float* bk,
                          const u16* Wvh, const u16* Wvl, const float* bv) {
        // lin -> Y (hi/lo, pre-BN)
        gemm_hl<1><<<dim3(128, 8, 1), 256, 0, stream>>>(
            inh, inl, Kin, Wh, Wl, Kin, Kin, bl, nullptr, Yh, Yl, 1024);
        bn_stats_hl<<<dim3(2048), 256, 0, stream>>>(Yh, Yl, mean, rstd);
        bn_apply_hl<<<dim3(16384), 256, 0, stream>>>(Yh, Yl, mean, rstd, g, be);
        // per-batch pool buffers
        float* s_b = (float*)P;                       // 16,777,216 B
        u16* qh = (u16*)(P + 16777216);  u16* ql = (u16*)(P + 20971520);
        u16* kh = (u16*)(P + 25165824); u16* kl = (u16*)(P + 29360128);
        u16* vh = (u16*)(P + 33554432); u16* vl = (u16*)(P + 37748736);
        u16* vth = (u16*)(P + 41943040); u16* vtl = (u16*)(P + 46137344);
        for (int b = 0; b < 8; ++b) {
            const long bo = (long)b * 2097152;
            gemm_hl<1><<<dim3(16, 8, 1), 256, 0, stream>>>(
                Yh + bo, Yl + bo, 1024, Wqh, Wql, 1024, 1024, bq, nullptr, qh, ql, 1024);
            gemm_hl<1><<<dim3(16, 8, 1), 256, 0, stream>>>(
                Yh + bo, Yl + bo, 1024, Wkh, Wkl, 1024, 1024, bk, nullptr, kh, kl, 1024);
            gemm_hl<1><<<dim3(16, 8, 1), 256, 0, stream>>>(
                Yh + bo, Yl + bo, 1024, Wvh, Wvl, 1024, 1024, bv, nullptr, vh, vl, 1024);
            transpose_hl2<<<dim3(32, 16, 2), 256, 0, stream>>>(vh, vth, vl, vtl);
            gemm_hl<0><<<dim3(16, 16, 1), 256, 0, stream>>>(
                qh, ql, 1024, kh, kl, 1024, 1024, nullptr, s_b, nullptr, nullptr, 2048);
            softmax_hl<<<dim3(2048), 256, 0, stream>>>(s_b);
            // AV -> o[b], overwrites h[b] (dead after v-gemm above)
            gemm_hl<1><<<dim3(16, 8, 1), 256, 0, stream>>>(
                (const u16*)s_b, (const u16*)s_b + 2048, 4096, vth, vtl, 2048,
                2048, nullptr, nullptr, Yh + bo, Yl + bo, 1024);
        }
    };

    // ---- layer 1: X=R2 (x), Y=R1, pool in R2 ----
    full_layer(xh, xl, 512, R1h, R1l, (char*)R2h,
               W1h, W1l, b1, g1, be1,
               Wq1h, Wq1l, bq1, Wk1h, Wk1l, bk1, Wv1h, Wv1l, bv1);
    // ---- layer 2: X=R1 (o), Y=R2, pool in R1 ----
    full_layer(R1h, R1l, 1024, R2h, R2l, (char*)R1h,
               W2h, W2l, b2, g2, be2,
               Wq2h, Wq2l, bq2, Wk2h, Wk2l, bk2, Wv2h, Wv2l, bv2);
    // ---- final linear: o2 (R2) @ W3sn^T -> d_out fp32 ----
    gemm_hl<0><<<dim3(128, 4, 1), 256, 0, stream>>>(
        R2h, R2l, 1024, W3h, W3l, 1024, 1024, b3,
        (float*)d_out, nullptr, nullptr, 512);
}

// Round 7
// 2704.901 us; speedup vs baseline: 1.8408x; 1.8408x over previous
//
#include <hip/hip_runtime.h>

typedef unsigned short u16;
typedef unsigned int u32;
typedef short bf16x8 __attribute__((ext_vector_type(8)));
typedef float f32x4 __attribute__((ext_vector_type(4)));
typedef unsigned short u16x4 __attribute__((ext_vector_type(4)));

// ---------- bf16 helpers (RNE) ----------
__device__ __forceinline__ u16 f2bf(float f) {
    u32 u = __float_as_uint(f);
    u32 r = (u + 0x7FFFu + ((u >> 16) & 1u)) >> 16;
    return (u16)r;
}
__device__ __forceinline__ float bf2f(u16 h) { return __uint_as_float(((u32)h) << 16); }

// ---------- global -> LDS direct ----------
__device__ __forceinline__ void gll16(const void* g, void* l) {
    auto gp = reinterpret_cast<const __attribute__((address_space(1))) u32*>(
        reinterpret_cast<uintptr_t>(g));
    auto lp = reinterpret_cast<__attribute__((address_space(3))) u32*>(
        reinterpret_cast<uintptr_t>(l));
    __builtin_amdgcn_global_load_lds(gp, lp, 16, 0, 0);
}

// ---------- sentinel fill (diagnoses ws-too-small) ----------
__global__ void fill_f32(float* __restrict__ p, float v, int n) {
    int i = blockIdx.x * 256 + threadIdx.x;
    if (i < n) p[i] = v;
}

// ---------- split fp32 -> (hi,lo) bf16, optional 1/sigma scale ----------
__device__ __forceinline__ void split_body(const float* __restrict__ src, float sc,
                                           u16* __restrict__ hi, u16* __restrict__ lo, int i) {
    float4 f = reinterpret_cast<const float4*>(src)[i];
    float v0 = f.x * sc, v1 = f.y * sc, v2 = f.z * sc, v3 = f.w * sc;
    u16 h0 = f2bf(v0), h1 = f2bf(v1), h2 = f2bf(v2), h3 = f2bf(v3);
    u16x4 H = {h0, h1, h2, h3};
    u16x4 L = {f2bf(v0 - bf2f(h0)), f2bf(v1 - bf2f(h1)), f2bf(v2 - bf2f(h2)), f2bf(v3 - bf2f(h3))};
    reinterpret_cast<u16x4*>(hi)[i] = H;
    reinterpret_cast<u16x4*>(lo)[i] = L;
}

__global__ void split_hl(const float* __restrict__ src, const float* __restrict__ sigma,
                         u16* __restrict__ hi, u16* __restrict__ lo, int n4) {
    int i = blockIdx.x * 256 + threadIdx.x;
    if (i >= n4) return;
    float sc = sigma ? (1.0f / *sigma) : 1.0f;
    split_body(src, sc, hi, lo, i);
}

struct SJ { const float* src; u16* hi; u16* lo; };
struct SJ6 { SJ j[6]; };
__global__ void split_hl6(SJ6 jobs, int n4) {
    int i = blockIdx.x * 256 + threadIdx.x;
    if (i >= n4) return;
    const SJ J = jobs.j[blockIdx.y];
    split_body(J.src, 1.0f, J.hi, J.lo, i);
}

// ---------- spectral norm (tiny, deterministic) ----------
__global__ void sn_col(const float* __restrict__ W, const float* __restrict__ u,
                       int N, int K, float* __restrict__ vraw) {
    int j = blockIdx.x * 256 + threadIdx.x;
    if (j >= K) return;
    float acc = 0.f;
#pragma unroll 4
    for (int i = 0; i < N; ++i) acc = fmaf(W[(long)i * K + j], u[i], acc);
    vraw[j] = acc;
}

__global__ void sn_norm(const float* __restrict__ vraw, int K, float* __restrict__ vn) {
    const int t = threadIdx.x;
    float x = (t < K) ? vraw[t] : 0.f;
    float s = x * x;
#pragma unroll
    for (int o = 1; o < 64; o <<= 1) s += __shfl_xor(s, o);
    __shared__ float red[16];
    if ((t & 63) == 0) red[t >> 6] = s;
    __syncthreads();
    if (t == 0) {
        float S = 0.f;
        for (int i = 0; i < 16; ++i) S += red[i];
        red[0] = 1.0f / (sqrtf(S) + 1e-12f);
    }
    __syncthreads();
    if (t < K) vn[t] = x * red[0];
}

__global__ void sn_dot(const float* __restrict__ W, const float* __restrict__ vn,
                       const float* __restrict__ u, int N, int K, float* __restrict__ rowdot) {
    const int row = (blockIdx.x << 2) + (threadIdx.x >> 6);
    const int l = threadIdx.x & 63;
    const float* wr = W + (long)row * K;
    float s = 0.f;
    for (int j = l; j < K; j += 64) s = fmaf(wr[j], vn[j], s);
#pragma unroll
    for (int o = 1; o < 64; o <<= 1) s += __shfl_xor(s, o);
    if (l == 0) rowdot[row] = u[row] * s;
}

__global__ void sn_sig(const float* __restrict__ rd, int N, float* __restrict__ sig) {
    const int t = threadIdx.x;
    float x = (t < N) ? rd[t] : 0.f;
#pragma unroll
    for (int o = 1; o < 64; o <<= 1) x += __shfl_xor(x, o);
    __shared__ float red[16];
    if ((t & 63) == 0) red[t >> 6] = x;
    __syncthreads();
    if (t == 0) {
        float S = 0.f;
        for (int i = 0; i < 16; ++i) S += red[i];
        *sig = S;
    }
}

// ---------- shared 128x128x(K) hi/lo GEMM core: C[m,n]=sum_k A[m,k]*B[n,k] ----------
template <int EPI>
__device__ __forceinline__ void gemm_core(
    const u16* __restrict__ Ah, const u16* __restrict__ Al, int lda,
    const u16* __restrict__ Bh, const u16* __restrict__ Bl, int ldb,
    int K, const float* __restrict__ bias,
    float* __restrict__ Cf, u16* __restrict__ Chi, u16* __restrict__ Clo, int ldc) {
    __shared__ u16 lds[16384];  // Ahi | Alo | Bhi | Blo, each [128][32] bf16 (8KB)
    const int tid = threadIdx.x;
    const int l = tid & 63;
    const int w = tid >> 6;
    const int m0 = blockIdx.x << 7;
    const int n0 = blockIdx.y << 7;

    const int srow = (w << 4) + (l >> 2);
    const int scol = (l & 3) << 3;
    const long offA0 = (long)(m0 + srow) * lda + scol;
    const long offA1 = offA0 + ((long)lda << 6);
    const long offB0 = (long)(n0 + srow) * ldb + scol;
    const long offB1 = offB0 + ((long)ldb << 6);
    char* lb = (char*)lds + (w << 10);

    f32x4 acc[4][4];
#pragma unroll
    for (int i = 0; i < 4; ++i)
#pragma unroll
        for (int j = 0; j < 4; ++j) acc[i][j] = (f32x4){0.f, 0.f, 0.f, 0.f};

    const int wm = (w >> 1) << 6;
    const int wn = (w & 1) << 6;
    const int fq = (l >> 4) << 3;
    const int fr = l & 15;

    for (int k0 = 0; k0 < K; k0 += 32) {
        __syncthreads();
        gll16(Ah + offA0 + k0, lb);
        gll16(Ah + offA1 + k0, lb + 4096);
        gll16(Al + offA0 + k0, lb + 8192);
        gll16(Al + offA1 + k0, lb + 12288);
        gll16(Bh + offB0 + k0, lb + 16384);
        gll16(Bh + offB1 + k0, lb + 20480);
        gll16(Bl + offB0 + k0, lb + 24576);
        gll16(Bl + offB1 + k0, lb + 28672);
        __syncthreads();

        bf16x8 a0[4], a1[4], b0[4], b1[4];
#pragma unroll
        for (int mi = 0; mi < 4; ++mi) {
            int r = wm + (mi << 4) + fr;
            a0[mi] = *(const bf16x8*)(lds + (r << 5) + fq);
            a1[mi] = *(const bf16x8*)(lds + 4096 + (r << 5) + fq);
        }
#pragma unroll
        for (int ni = 0; ni < 4; ++ni) {
            int r = wn + (ni << 4) + fr;
            b0[ni] = *(const bf16x8*)(lds + 8192 + (r << 5) + fq);
            b1[ni] = *(const bf16x8*)(lds + 12288 + (r << 5) + fq);
        }
#pragma unroll
        for (int mi = 0; mi < 4; ++mi)
#pragma unroll
            for (int ni = 0; ni < 4; ++ni) {
                acc[mi][ni] = __builtin_amdgcn_mfma_f32_16x16x32_bf16(a0[mi], b0[ni], acc[mi][ni], 0, 0, 0);
                acc[mi][ni] = __builtin_amdgcn_mfma_f32_16x16x32_bf16(a0[mi], b1[ni], acc[mi][ni], 0, 0, 0);
                acc[mi][ni] = __builtin_amdgcn_mfma_f32_16x16x32_bf16(a1[mi], b0[ni], acc[mi][ni], 0, 0, 0);
            }
    }

    const int r0 = (l >> 4) << 2;
#pragma unroll
    for (int mi = 0; mi < 4; ++mi) {
#pragma unroll
        for (int ni = 0; ni < 4; ++ni) {
            const int gc = n0 + wn + (ni << 4) + fr;
            const float bv = bias ? bias[gc] : 0.0f;
#pragma unroll
            for (int r = 0; r < 4; ++r) {
                const int gr = m0 + wm + (mi << 4) + r0 + r;
                float v = acc[mi][ni][r] + bv;
                if (EPI == 0) {
                    Cf[(long)gr * ldc + gc] = v;
                } else {
                    u16 h = f2bf(v);
                    Chi[(long)gr * ldc + gc] = h;
                    Clo[(long)gr * ldc + gc] = f2bf(v - bf2f(h));
                }
            }
        }
    }
}

// z-batched wrapper: independent strides per operand (elements of their type)
template <int EPI>
__global__ __launch_bounds__(256, 4) void gemm_hl(
    const u16* __restrict__ Ah, const u16* __restrict__ Al, int lda, long sA,
    const u16* __restrict__ Bh, const u16* __restrict__ Bl, int ldb, long sB,
    int K, const float* __restrict__ bias,
    float* Cf, u16* Chi, u16* Clo, int ldc, long sC) {
    const long z = blockIdx.z;
    gemm_core<EPI>(Ah + z * sA, Al + z * sA, lda, Bh + z * sB, Bl + z * sB, ldb, K, bias,
                   EPI == 0 ? Cf + z * sC : nullptr,
                   EPI == 1 ? Chi + z * sC : nullptr,
                   EPI == 1 ? Clo + z * sC : nullptr, ldc);
}

// fused Q/K/V projection: z = p*3 + j; j selects weight/bias/output, p batch offset
struct QKVA {
    const u16* Bh[3]; const u16* Bl[3]; const float* bi[3];
    u16* Ch[3]; u16* Cl[3];
};
__global__ __launch_bounds__(256, 4) void gemm_qkv(
    const u16* __restrict__ Ah, const u16* __restrict__ Al, int lda, long sAp,
    QKVA S, long sCp, int K) {
    const int j = blockIdx.z % 3;
    const long p = blockIdx.z / 3;
    gemm_core<1>(Ah + p * sAp, Al + p * sAp, lda, S.Bh[j], S.Bl[j], K, K, S.bi[j],
                 nullptr, S.Ch[j] + p * sCp, S.Cl[j] + p * sCp, 1024);
}

// ---------- BatchNorm over channel s of [8][2048(s)][1024], on hi/lo planes ----------
__global__ void bn_stats_hl(const u16* __restrict__ hh, const u16* __restrict__ hl,
                            float* __restrict__ mean, float* __restrict__ rstd) {
    const int s = blockIdx.x, t = threadIdx.x;
    float sum = 0.f, sq = 0.f;
#pragma unroll
    for (int b = 0; b < 8; ++b) {
        long base = ((long)b * 2048 + s) * 1024 + (t << 2);
        u16x4 H = *(const u16x4*)(hh + base);
        u16x4 L = *(const u16x4*)(hl + base);
        float v0 = bf2f(H.x) + bf2f(L.x), v1 = bf2f(H.y) + bf2f(L.y);
        float v2 = bf2f(H.z) + bf2f(L.z), v3 = bf2f(H.w) + bf2f(L.w);
        sum += v0 + v1 + v2 + v3;
        sq += v0 * v0 + v1 * v1 + v2 * v2 + v3 * v3;
    }
#pragma unroll
    for (int o = 1; o < 64; o <<= 1) { sum += __shfl_xor(sum, o); sq += __shfl_xor(sq, o); }
    __shared__ float ss[4], qq[4];
    if ((t & 63) == 0) { ss[t >> 6] = sum; qq[t >> 6] = sq; }
    __syncthreads();
    if (t == 0) {
        float S = ss[0] + ss[1] + ss[2] + ss[3];
        float Q = qq[0] + qq[1] + qq[2] + qq[3];
        float m = S * (1.0f / 8192.0f);
        float var = Q * (1.0f / 8192.0f) - m * m;
        mean[s] = m;
        rstd[s] = rsqrtf(var + 1e-5f);
    }
}

__global__ void bn_apply_hl(u16* __restrict__ hh, u16* __restrict__ hl,
                            const float* __restrict__ mean, const float* __restrict__ rstd,
                            const float* __restrict__ g, const float* __restrict__ be) {
    const long i = ((long)blockIdx.x * 256 + threadIdx.x) << 2;
    const int s = (int)((i >> 10) & 2047);
    const float a = rstd[s] * g[s];
    const float c = fmaf(-mean[s], a, be[s]);
    u16x4 H = *(const u16x4*)(hh + i);
    u16x4 L = *(const u16x4*)(hl + i);
    float v0 = fmaf(bf2f(H.x) + bf2f(L.x), a, c);
    float v1 = fmaf(bf2f(H.y) + bf2f(L.y), a, c);
    float v2 = fmaf(bf2f(H.z) + bf2f(L.z), a, c);
    float v3 = fmaf(bf2f(H.w) + bf2f(L.w), a, c);
    v0 = v0 > 0.f ? v0 : 0.2f * v0;
    v1 = v1 > 0.f ? v1 : 0.2f * v1;
    v2 = v2 > 0.f ? v2 : 0.2f * v2;
    v3 = v3 > 0.f ? v3 : 0.2f * v3;
    u16 h0 = f2bf(v0), h1 = f2bf(v1), h2 = f2bf(v2), h3 = f2bf(v3);
    u16x4 HO = {h0, h1, h2, h3};
    u16x4 LO = {f2bf(v0 - bf2f(h0)), f2bf(v1 - bf2f(h1)), f2bf(v2 - bf2f(h2)), f2bf(v3 - bf2f(h3))};
    *(u16x4*)(hh + i) = HO;
    *(u16x4*)(hl + i) = LO;
}

// ---------- softmax rows of 2048, in-place fp32 -> (hi,lo) bf16; p = block>>11 ----------
__global__ __launch_bounds__(256) void softmax_hl(float* __restrict__ scores, long pstride) {
    const long p = blockIdx.x >> 11;
    float* pp = scores + p * pstride + ((long)(blockIdx.x & 2047) << 11);
    const int t = threadIdx.x;
    float4 f0 = *(const float4*)(pp + (t << 2));
    float4 f1 = *(const float4*)(pp + 1024 + (t << 2));
    float mx = fmaxf(fmaxf(fmaxf(f0.x, f0.y), fmaxf(f0.z, f0.w)),
                     fmaxf(fmaxf(f1.x, f1.y), fmaxf(f1.z, f1.w)));
#pragma unroll
    for (int o = 1; o < 64; o <<= 1) mx = fmaxf(mx, __shfl_xor(mx, o));
    __shared__ float red[4];
    if ((t & 63) == 0) red[t >> 6] = mx;
    __syncthreads();
    mx = fmaxf(fmaxf(red[0], red[1]), fmaxf(red[2], red[3]));
    float e0 = expf(f0.x - mx), e1 = expf(f0.y - mx), e2 = expf(f0.z - mx), e3 = expf(f0.w - mx);
    float e4 = expf(f1.x - mx), e5 = expf(f1.y - mx), e6 = expf(f1.z - mx), e7 = expf(f1.w - mx);
    float s = ((e0 + e1) + (e2 + e3)) + ((e4 + e5) + (e6 + e7));
#pragma unroll
    for (int o = 1; o < 64; o <<= 1) s += __shfl_xor(s, o);
    __syncthreads();
    if ((t & 63) == 0) red[t >> 6] = s;
    __syncthreads();
    const float inv = 1.0f / ((red[0] + red[1]) + (red[2] + red[3]));
    e0 *= inv; e1 *= inv; e2 *= inv; e3 *= inv; e4 *= inv; e5 *= inv; e6 *= inv; e7 *= inv;
    u16* hi = (u16*)pp;
    u16* lo = hi + 2048;
    u16 h0 = f2bf(e0), h1 = f2bf(e1), h2 = f2bf(e2), h3 = f2bf(e3);
    u16 h4 = f2bf(e4), h5 = f2bf(e5), h6 = f2bf(e6), h7 = f2bf(e7);
    u16x4 H0 = {h0, h1, h2, h3}, H1 = {h4, h5, h6, h7};
    u16x4 L0 = {f2bf(e0 - bf2f(h0)), f2bf(e1 - bf2f(h1)), f2bf(e2 - bf2f(h2)), f2bf(e3 - bf2f(h3))};
    u16x4 L1 = {f2bf(e4 - bf2f(h4)), f2bf(e5 - bf2f(h5)), f2bf(e6 - bf2f(h6)), f2bf(e7 - bf2f(h7))};
    *(u16x4*)(hi + (t << 2)) = H0;
    *(u16x4*)(hi + 1024 + (t << 2)) = H1;
    *(u16x4*)(lo + (t << 2)) = L0;
    *(u16x4*)(lo + 1024 + (t << 2)) = L1;
}

// ---------- transpose [2048][1024] -> [1024][2048] (u16); z = plane + 2*p ----------
__global__ void transpose_hl2(const u16* __restrict__ src_hi, u16* __restrict__ dst_hi,
                              const u16* __restrict__ src_lo, u16* __restrict__ dst_lo,
                              long sp, long dp) {
    __shared__ u16 tile[64][68];
    const long p = blockIdx.z >> 1;
    const u16* src = ((blockIdx.z & 1) ? src_lo : src_hi) + p * sp;
    u16* dst = ((blockIdx.z & 1) ? dst_lo : dst_hi) + p * dp;
    const int t0 = blockIdx.x << 6, d0 = blockIdx.y << 6;
    const int rr = threadIdx.x >> 4, cc = (threadIdx.x & 15) << 2;
#pragma unroll
    for (int it = 0; it < 4; ++it) {
        int r = (it << 4) + rr;
        u16x4 v = *(const u16x4*)(src + (long)(t0 + r) * 1024 + d0 + cc);
        tile[r][cc] = v.x; tile[r][cc + 1] = v.y; tile[r][cc + 2] = v.z; tile[r][cc + 3] = v.w;
    }
    __syncthreads();
#pragma unroll
    for (int it = 0; it < 4; ++it) {
        int r = (it << 4) + rr;
        u16x4 o;
        o.x = tile[cc][r]; o.y = tile[cc + 1][r]; o.z = tile[cc + 2][r]; o.w = tile[cc + 3][r];
        *(u16x4*)(dst + (long)(d0 + r) * 2048 + t0 + cc) = o;
    }
}

// ======================= host launcher =======================
extern "C" void kernel_launch(void* const* d_in, const int* in_sizes, int n_in,
                              void* d_out, int out_size, void* d_ws, size_t ws_size,
                              hipStream_t stream) {
    const float* x = (const float*)d_in[0];
    const float* W1 = (const float*)d_in[1];
    const float* b1 = (const float*)d_in[2];
    const float* u1 = (const float*)d_in[3];
    const float* g1 = (const float*)d_in[4];
    const float* be1 = (const float*)d_in[5];
    const float* Wq1 = (const float*)d_in[6];  const float* bq1 = (const float*)d_in[7];
    const float* Wk1 = (const float*)d_in[8];  const float* bk1 = (const float*)d_in[9];
    const float* Wv1 = (const float*)d_in[10]; const float* bv1 = (const float*)d_in[11];
    const float* W2 = (const float*)d_in[12];  const float* b2 = (const float*)d_in[13];
    const float* u2 = (const float*)d_in[14];
    const float* g2 = (const float*)d_in[15];  const float* be2 = (const float*)d_in[16];
    const float* Wq2 = (const float*)d_in[17]; const float* bq2 = (const float*)d_in[18];
    const float* Wk2 = (const float*)d_in[19]; const float* bk2 = (const float*)d_in[20];
    const float* Wv2 = (const float*)d_in[21]; const float* bv2 = (const float*)d_in[22];
    const float* W3 = (const float*)d_in[23];  const float* b3 = (const float*)d_in[24];
    const float* u3 = (const float*)d_in[25];

    // PATH1 (>=160MiB+32KB): per-batch attention, pool aliased into input region.
    // PATH2 (>=256MiB): batch-PAIR pools (2x50.33MB) after WB; small scratch FS
    //   relocated into scores(0) (lifetimes disjoint: sn/bn smalls die before
    //   each layer's attention writes scores).
    const size_t NEED1 = 167804928ull;
    const size_t NEED2 = 268435456ull;
    if (ws_size < NEED1) {  // sentinel: error==12345 <=> this tripped
        fill_f32<<<dim3((out_size + 255) / 256), 256, 0, stream>>>((float*)d_out, 12345.0f, out_size);
        return;
    }
    const int nPair = (ws_size >= NEED2) ? 2 : 1;
    char* ws = (char*)d_ws;
    u16* R1h = (u16*)ws;                     u16* R1l = R1h + 16777216;
    u16* R2h = (u16*)(ws + 67108864);        u16* R2l = R2h + 16777216;
    u16* WBu = (u16*)(ws + 134217728);
    const long PSTRIDE = 50331648;           // pool pair stride, bytes
    char* pool2 = ws + 167772160;            // PATH2 pools (100.66MB)
    float* FS = (nPair == 2) ? (float*)pool2 : (float*)(ws + 167772160);

    u16* W1h = WBu;                 u16* W1l = WBu + 524288;
    u16* Wq1h = WBu + 1048576;      u16* Wq1l = WBu + 2097152;
    u16* Wk1h = WBu + 3145728;      u16* Wk1l = WBu + 4194304;
    u16* Wv1h = WBu + 5242880;      u16* Wv1l = WBu + 6291456;
    u16* W2h = WBu + 7340032;       u16* W2l = WBu + 8388608;
    u16* Wq2h = WBu + 9437184;      u16* Wq2l = WBu + 10485760;
    u16* Wk2h = WBu + 11534336;     u16* Wk2l = WBu + 12582912;
    u16* Wv2h = WBu + 13631488;     u16* Wv2l = WBu + 14680064;
    u16* W3h = WBu + 15728640;      u16* W3l = WBu + 16252928;

    float* vraw = FS;        float* vn = FS + 1024;
    float* rowdot = FS + 2048;
    float* sig1 = FS + 3072; float* sig2 = FS + 3073; float* sig3 = FS + 3074;
    float* mean = FS + 4096; float* rstd = FS + 6144;

    auto split = [&](const float* src, const float* sg, u16* hi, u16* lo, int nElem) {
        split_hl<<<dim3(nElem / 1024), 256, 0, stream>>>(src, sg, hi, lo, nElem / 4);
    };
    auto spec = [&](const float* W, const float* u, int N, int Kd, float* sg) {
        sn_col<<<dim3(Kd / 256), 256, 0, stream>>>(W, u, N, Kd, vraw);
        sn_norm<<<dim3(1), 1024, 0, stream>>>(vraw, Kd, vn);
        sn_dot<<<dim3(N / 4), 256, 0, stream>>>(W, vn, u, N, Kd, rowdot);
        sn_sig<<<dim3(1), 1024, 0, stream>>>(rowdot, N, sg);
    };

    // ---- weight prep ----
    u16* xh = R2h;  u16* xl = R2h + 8388608;   // x staged in R2 (dead after lin1)
    split(x, nullptr, xh, xl, 8388608);
    spec(W1, u1, 1024, 512, sig1);  split(W1, sig1, W1h, W1l, 524288);
    spec(W2, u2, 1024, 1024, sig2); split(W2, sig2, W2h, W2l, 1048576);
    spec(W3, u3, 512, 1024, sig3);  split(W3, sig3, W3h, W3l, 524288);
    SJ6 sj;
    sj.j[0] = {Wq1, Wq1h, Wq1l};
    sj.j[1] = {Wk1, Wk1h, Wk1l};
    sj.j[2] = {Wv1, Wv1h, Wv1l};
    sj.j[3] = {Wq2, Wq2h, Wq2l};
    sj.j[4] = {Wk2, Wk2h, Wk2l};
    sj.j[5] = {Wv2, Wv2h, Wv2l};
    split_hl6<<<dim3(1024, 6), 256, 0, stream>>>(sj, 262144);

    // full layer: X=(inh,inl); Y=(Yh,Yl); P = pool(0) base
    auto full_layer = [&](const u16* inh, const u16* inl, int Kin,
                          u16* Yh, u16* Yl, char* P,
                          const u16* Wh, const u16* Wl, const float* bl,
                          const float* g, const float* be,
                          const u16* Wqh, const u16* Wql, const float* bq,
                          const u16* Wkh, const u16* Wkl, const float* bk,
                          const u16* Wvh, const u16* Wvl, const float* bv) {
        gemm_hl<1><<<dim3(128, 8, 1), 256, 0, stream>>>(
            inh, inl, Kin, 0, Wh, Wl, Kin, 0, Kin, bl, nullptr, Yh, Yl, 1024, 0);
        bn_stats_hl<<<dim3(2048), 256, 0, stream>>>(Yh, Yl, mean, rstd);
        bn_apply_hl<<<dim3(16384), 256, 0, stream>>>(Yh, Yl, mean, rstd, g, be);
        // pool(0) interior
        float* s0 = (float*)P;
        u16* qh = (u16*)(P + 16777216); u16* ql = (u16*)(P + 20971520);
        u16* kh = (u16*)(P + 25165824); u16* kl = (u16*)(P + 29360128);
        u16* vh = (u16*)(P + 33554432); u16* vl = (u16*)(P + 37748736);
        u16* vth = (u16*)(P + 41943040); u16* vtl = (u16*)(P + 46137344);
        const long sPu = (nPair == 2) ? PSTRIDE / 2 : 0;   // pool stride, u16
        const long sPf = (nPair == 2) ? PSTRIDE / 4 : 0;   // pool stride, f32
        QKVA Q;
        Q.Bh[0] = Wqh; Q.Bl[0] = Wql; Q.bi[0] = bq; Q.Ch[0] = qh; Q.Cl[0] = ql;
        Q.Bh[1] = Wkh; Q.Bl[1] = Wkl; Q.bi[1] = bk; Q.Ch[1] = kh; Q.Cl[1] = kl;
        Q.Bh[2] = Wvh; Q.Bl[2] = Wvl; Q.bi[2] = bv; Q.Ch[2] = vh; Q.Cl[2] = vl;
        for (int b = 0; b < 8; b += nPair) {
            const long bo = (long)b * 2097152;
            gemm_qkv<<<dim3(16, 8, 3 * nPair), 256, 0, stream>>>(
                Yh + bo, Yl + bo, 1024, 2097152, Q, sPu, 1024);
            transpose_hl2<<<dim3(32, 16, 2 * nPair), 256, 0, stream>>>(
                vh, vth, vl, vtl, sPu, sPu);
            gemm_hl<0><<<dim3(16, 16, nPair), 256, 0, stream>>>(
                qh, ql, 1024, sPu, kh, kl, 1024, sPu,
                1024, nullptr, s0, nullptr, nullptr, 2048, sPf);
            softmax_hl<<<dim3(2048 * nPair), 256, 0, stream>>>(s0, sPf);
            gemm_hl<1><<<dim3(16, 8, nPair), 256, 0, stream>>>(
                (const u16*)s0, (const u16*)s0 + 2048, 4096, sPu, vth, vtl, 2048, sPu,
                2048, nullptr, nullptr, Yh + bo, Yl + bo, 1024, 2097152);
        }
    };

    // PATH1: pool aliases the layer-input region (dead by attention time).
    char* P_l1 = (nPair == 2) ? pool2 : (char*)R2h;
    char* P_l2 = (nPair == 2) ? pool2 : (char*)R1h;

    // ---- layer 1: X=R2 (x), Y=R1 ----
    full_layer(xh, xl, 512, R1h, R1l, P_l1,
               W1h, W1l, b1, g1, be1,
               Wq1h, Wq1l, bq1, Wk1h, Wk1l, bk1, Wv1h, Wv1l, bv1);
    // ---- layer 2: X=R1 (o1), Y=R2 ----
    full_layer(R1h, R1l, 1024, R2h, R2l, P_l2,
               W2h, W2l, b2, g2, be2,
               Wq2h, Wq2l, bq2, Wk2h, Wk2l, bk2, Wv2h, Wv2l, bv2);
    // ---- final linear: o2 (R2) @ W3sn^T -> d_out fp32 ----
    gemm_hl<0><<<dim3(128, 4, 1), 256, 0, stream>>>(
        R2h, R2l, 1024, 0, W3h, W3l, 1024, 0, 1024, b3,
        (float*)d_out, nullptr, nullptr, 512, 0);
}

// Round 9
// 2411.762 us; speedup vs baseline: 2.0645x; 1.1215x over previous
//
#include <hip/hip_runtime.h>

typedef unsigned short u16;
typedef unsigned int u32;
typedef short bf16x8 __attribute__((ext_vector_type(8)));
typedef float f32x4 __attribute__((ext_vector_type(4)));
typedef unsigned short u16x4 __attribute__((ext_vector_type(4)));

// ---------- bf16 helpers (RNE) ----------
__device__ __forceinline__ u16 f2bf(float f) {
    u32 u = __float_as_uint(f);
    u32 r = (u + 0x7FFFu + ((u >> 16) & 1u)) >> 16;
    return (u16)r;
}
__device__ __forceinline__ float bf2f(u16 h) { return __uint_as_float(((u32)h) << 16); }

// ---------- global -> LDS direct ----------
__device__ __forceinline__ void gll16(const void* g, void* l) {
    auto gp = reinterpret_cast<const __attribute__((address_space(1))) u32*>(
        reinterpret_cast<uintptr_t>(g));
    auto lp = reinterpret_cast<__attribute__((address_space(3))) u32*>(
        reinterpret_cast<uintptr_t>(l));
    __builtin_amdgcn_global_load_lds(gp, lp, 16, 0, 0);
}

// ---------- sentinel fill (diagnoses ws-too-small) ----------
__global__ void fill_f32(float* __restrict__ p, float v, int n) {
    int i = blockIdx.x * 256 + threadIdx.x;
    if (i < n) p[i] = v;
}

// ---------- split fp32 -> (hi,lo) bf16, optional 1/sigma scale ----------
__device__ __forceinline__ void split_body(const float* __restrict__ src, float sc,
                                           u16* __restrict__ hi, u16* __restrict__ lo, int i) {
    float4 f = reinterpret_cast<const float4*>(src)[i];
    float v0 = f.x * sc, v1 = f.y * sc, v2 = f.z * sc, v3 = f.w * sc;
    u16 h0 = f2bf(v0), h1 = f2bf(v1), h2 = f2bf(v2), h3 = f2bf(v3);
    u16x4 H = {h0, h1, h2, h3};
    u16x4 L = {f2bf(v0 - bf2f(h0)), f2bf(v1 - bf2f(h1)), f2bf(v2 - bf2f(h2)), f2bf(v3 - bf2f(h3))};
    reinterpret_cast<u16x4*>(hi)[i] = H;
    reinterpret_cast<u16x4*>(lo)[i] = L;
}

__global__ void split_hl(const float* __restrict__ src, const float* __restrict__ sigma,
                         u16* __restrict__ hi, u16* __restrict__ lo, int n4) {
    int i = blockIdx.x * 256 + threadIdx.x;
    if (i >= n4) return;
    float sc = sigma ? (1.0f / *sigma) : 1.0f;
    split_body(src, sc, hi, lo, i);
}

struct SJ { const float* src; u16* hi; u16* lo; };
struct SJ6 { SJ j[6]; };
__global__ void split_hl6(SJ6 jobs, int n4) {
    int i = blockIdx.x * 256 + threadIdx.x;
    if (i >= n4) return;
    const SJ J = jobs.j[blockIdx.y];
    split_body(J.src, 1.0f, J.hi, J.lo, i);
}

// ---------- spectral norm ----------
// stage A: vpart[c][j] = sum_{i in chunk c} W[i][j]*u[i]   (16 chunks -> 16x parallel)
__global__ void sn_col_part(const float* __restrict__ W, const float* __restrict__ u,
                            int N, int K, float* __restrict__ vpart) {
    const int j = blockIdx.x * 256 + threadIdx.x;
    if (j >= K) return;
    const int chunk = N >> 4;
    const int i0 = blockIdx.y * chunk;
    float acc = 0.f;
#pragma unroll 8
    for (int i = i0; i < i0 + chunk; ++i) acc = fmaf(W[(long)i * K + j], u[i], acc);
    vpart[(long)blockIdx.y * K + j] = acc;
}

// stage B: reduce 16 partials, normalize -> vn
__global__ void sn_norm16(const float* __restrict__ vpart, int K, float* __restrict__ vn) {
    const int t = threadIdx.x;
    float x = 0.f;
    if (t < K) {
#pragma unroll
        for (int c = 0; c < 16; ++c) x += vpart[(long)c * K + t];
    }
    float s = x * x;
#pragma unroll
    for (int o = 1; o < 64; o <<= 1) s += __shfl_xor(s, o);
    __shared__ float red[16];
    if ((t & 63) == 0) red[t >> 6] = s;
    __syncthreads();
    if (t == 0) {
        float S = 0.f;
        for (int i = 0; i < 16; ++i) S += red[i];
        red[0] = 1.0f / (sqrtf(S) + 1e-12f);
    }
    __syncthreads();
    if (t < K) vn[t] = x * red[0];
}

__global__ void sn_dot(const float* __restrict__ W, const float* __restrict__ vn,
                       const float* __restrict__ u, int N, int K, float* __restrict__ rowdot) {
    const int row = (blockIdx.x << 2) + (threadIdx.x >> 6);
    const int l = threadIdx.x & 63;
    const float* wr = W + (long)row * K;
    float s = 0.f;
    for (int j = l; j < K; j += 64) s = fmaf(wr[j], vn[j], s);
#pragma unroll
    for (int o = 1; o < 64; o <<= 1) s += __shfl_xor(s, o);
    if (l == 0) rowdot[row] = u[row] * s;
}

__global__ void sn_sig(const float* __restrict__ rd, int N, float* __restrict__ sig) {
    const int t = threadIdx.x;
    float x = (t < N) ? rd[t] : 0.f;
#pragma unroll
    for (int o = 1; o < 64; o <<= 1) x += __shfl_xor(x, o);
    __shared__ float red[16];
    if ((t & 63) == 0) red[t >> 6] = x;
    __syncthreads();
    if (t == 0) {
        float S = 0.f;
        for (int i = 0; i < 16; ++i) S += red[i];
        *sig = S;
    }
}

// ---------- shared 128x128x(K) hi/lo GEMM core: C[m,n]=sum_k A[m,k]*B[n,k] ----------
template <int EPI>
__device__ __forceinline__ void gemm_core(
    const u16* __restrict__ Ah, const u16* __restrict__ Al, int lda,
    const u16* __restrict__ Bh, const u16* __restrict__ Bl, int ldb,
    int K, const float* __restrict__ bias,
    float* __restrict__ Cf, u16* __restrict__ Chi, u16* __restrict__ Clo, int ldc) {
    __shared__ u16 lds[16384];  // Ahi | Alo | Bhi | Blo, each [128][32] bf16 (8KB)
    const int tid = threadIdx.x;
    const int l = tid & 63;
    const int w = tid >> 6;
    const int m0 = blockIdx.x << 7;
    const int n0 = blockIdx.y << 7;

    const int srow = (w << 4) + (l >> 2);
    const int scol = (l & 3) << 3;
    const long offA0 = (long)(m0 + srow) * lda + scol;
    const long offA1 = offA0 + ((long)lda << 6);
    const long offB0 = (long)(n0 + srow) * ldb + scol;
    const long offB1 = offB0 + ((long)ldb << 6);
    char* lb = (char*)lds + (w << 10);

    f32x4 acc[4][4];
#pragma unroll
    for (int i = 0; i < 4; ++i)
#pragma unroll
        for (int j = 0; j < 4; ++j) acc[i][j] = (f32x4){0.f, 0.f, 0.f, 0.f};

    const int wm = (w >> 1) << 6;
    const int wn = (w & 1) << 6;
    const int fq = (l >> 4) << 3;
    const int fr = l & 15;

    for (int k0 = 0; k0 < K; k0 += 32) {
        __syncthreads();
        gll16(Ah + offA0 + k0, lb);
        gll16(Ah + offA1 + k0, lb + 4096);
        gll16(Al + offA0 + k0, lb + 8192);
        gll16(Al + offA1 + k0, lb + 12288);
        gll16(Bh + offB0 + k0, lb + 16384);
        gll16(Bh + offB1 + k0, lb + 20480);
        gll16(Bl + offB0 + k0, lb + 24576);
        gll16(Bl + offB1 + k0, lb + 28672);
        __syncthreads();

        bf16x8 a0[4], a1[4], b0[4], b1[4];
#pragma unroll
        for (int mi = 0; mi < 4; ++mi) {
            int r = wm + (mi << 4) + fr;
            a0[mi] = *(const bf16x8*)(lds + (r << 5) + fq);
            a1[mi] = *(const bf16x8*)(lds + 4096 + (r << 5) + fq);
        }
#pragma unroll
        for (int ni = 0; ni < 4; ++ni) {
            int r = wn + (ni << 4) + fr;
            b0[ni] = *(const bf16x8*)(lds + 8192 + (r << 5) + fq);
            b1[ni] = *(const bf16x8*)(lds + 12288 + (r << 5) + fq);
        }
#pragma unroll
        for (int mi = 0; mi < 4; ++mi)
#pragma unroll
            for (int ni = 0; ni < 4; ++ni) {
                acc[mi][ni] = __builtin_amdgcn_mfma_f32_16x16x32_bf16(a0[mi], b0[ni], acc[mi][ni], 0, 0, 0);
                acc[mi][ni] = __builtin_amdgcn_mfma_f32_16x16x32_bf16(a0[mi], b1[ni], acc[mi][ni], 0, 0, 0);
                acc[mi][ni] = __builtin_amdgcn_mfma_f32_16x16x32_bf16(a1[mi], b0[ni], acc[mi][ni], 0, 0, 0);
            }
    }

    const int r0 = (l >> 4) << 2;
#pragma unroll
    for (int mi = 0; mi < 4; ++mi) {
#pragma unroll
        for (int ni = 0; ni < 4; ++ni) {
            const int gc = n0 + wn + (ni << 4) + fr;
            const float bv = bias ? bias[gc] : 0.0f;
#pragma unroll
            for (int r = 0; r < 4; ++r) {
                const int gr = m0 + wm + (mi << 4) + r0 + r;
                float v = acc[mi][ni][r] + bv;
                if (EPI == 0) {
                    Cf[(long)gr * ldc + gc] = v;
                } else {
                    u16 h = f2bf(v);
                    Chi[(long)gr * ldc + gc] = h;
                    Clo[(long)gr * ldc + gc] = f2bf(v - bf2f(h));
                }
            }
        }
    }
}

// z-batched wrapper: independent strides per operand (elements of their type)
template <int EPI>
__global__ __launch_bounds__(256, 4) void gemm_hl(
    const u16* __restrict__ Ah, const u16* __restrict__ Al, int lda, long sA,
    const u16* __restrict__ Bh, const u16* __restrict__ Bl, int ldb, long sB,
    int K, const float* __restrict__ bias,
    float* Cf, u16* Chi, u16* Clo, int ldc, long sC) {
    const long z = blockIdx.z;
    gemm_core<EPI>(Ah + z * sA, Al + z * sA, lda, Bh + z * sB, Bl + z * sB, ldb, K, bias,
                   EPI == 0 ? Cf + z * sC : nullptr,
                   EPI == 1 ? Chi + z * sC : nullptr,
                   EPI == 1 ? Clo + z * sC : nullptr, ldc);
}

// fused Q/K/V projection: z = p*3 + j; j selects weight/bias/output, p batch offset
struct QKVA {
    const u16* Bh[3]; const u16* Bl[3]; const float* bi[3];
    u16* Ch[3]; u16* Cl[3];
};
__global__ __launch_bounds__(256, 4) void gemm_qkv(
    const u16* __restrict__ Ah, const u16* __restrict__ Al, int lda, long sAp,
    QKVA S, long sCp, int K) {
    const int j = blockIdx.z % 3;
    const long p = blockIdx.z / 3;
    gemm_core<1>(Ah + p * sAp, Al + p * sAp, lda, S.Bh[j], S.Bl[j], K, K, S.bi[j],
                 nullptr, S.Ch[j] + p * sCp, S.Cl[j] + p * sCp, 1024);
}

// ---------- BatchNorm over channel s of [8][2048(s)][1024], on hi/lo planes ----------
__global__ void bn_stats_hl(const u16* __restrict__ hh, const u16* __restrict__ hl,
                            float* __restrict__ mean, float* __restrict__ rstd) {
    const int s = blockIdx.x, t = threadIdx.x;
    float sum = 0.f, sq = 0.f;
#pragma unroll
    for (int b = 0; b < 8; ++b) {
        long base = ((long)b * 2048 + s) * 1024 + (t << 2);
        u16x4 H = *(const u16x4*)(hh + base);
        u16x4 L = *(const u16x4*)(hl + base);
        float v0 = bf2f(H.x) + bf2f(L.x), v1 = bf2f(H.y) + bf2f(L.y);
        float v2 = bf2f(H.z) + bf2f(L.z), v3 = bf2f(H.w) + bf2f(L.w);
        sum += v0 + v1 + v2 + v3;
        sq += v0 * v0 + v1 * v1 + v2 * v2 + v3 * v3;
    }
#pragma unroll
    for (int o = 1; o < 64; o <<= 1) { sum += __shfl_xor(sum, o); sq += __shfl_xor(sq, o); }
    __shared__ float ss[4], qq[4];
    if ((t & 63) == 0) { ss[t >> 6] = sum; qq[t >> 6] = sq; }
    __syncthreads();
    if (t == 0) {
        float S = ss[0] + ss[1] + ss[2] + ss[3];
        float Q = qq[0] + qq[1] + qq[2] + qq[3];
        float m = S * (1.0f / 8192.0f);
        float var = Q * (1.0f / 8192.0f) - m * m;
        mean[s] = m;
        rstd[s] = rsqrtf(var + 1e-5f);
    }
}

__global__ void bn_apply_hl(u16* __restrict__ hh, u16* __restrict__ hl,
                            const float* __restrict__ mean, const float* __restrict__ rstd,
                            const float* __restrict__ g, const float* __restrict__ be) {
    const long i = ((long)blockIdx.x * 256 + threadIdx.x) << 2;
    const int s = (int)((i >> 10) & 2047);
    const float a = rstd[s] * g[s];
    const float c = fmaf(-mean[s], a, be[s]);
    u16x4 H = *(const u16x4*)(hh + i);
    u16x4 L = *(const u16x4*)(hl + i);
    float v0 = fmaf(bf2f(H.x) + bf2f(L.x), a, c);
    float v1 = fmaf(bf2f(H.y) + bf2f(L.y), a, c);
    float v2 = fmaf(bf2f(H.z) + bf2f(L.z), a, c);
    float v3 = fmaf(bf2f(H.w) + bf2f(L.w), a, c);
    v0 = v0 > 0.f ? v0 : 0.2f * v0;
    v1 = v1 > 0.f ? v1 : 0.2f * v1;
    v2 = v2 > 0.f ? v2 : 0.2f * v2;
    v3 = v3 > 0.f ? v3 : 0.2f * v3;
    u16 h0 = f2bf(v0), h1 = f2bf(v1), h2 = f2bf(v2), h3 = f2bf(v3);
    u16x4 HO = {h0, h1, h2, h3};
    u16x4 LO = {f2bf(v0 - bf2f(h0)), f2bf(v1 - bf2f(h1)), f2bf(v2 - bf2f(h2)), f2bf(v3 - bf2f(h3))};
    *(u16x4*)(hh + i) = HO;
    *(u16x4*)(hl + i) = LO;
}

// ---------- softmax rows of 2048, in-place fp32 -> (hi,lo) bf16; p = block>>11 ----------
__global__ __launch_bounds__(256) void softmax_hl(float* __restrict__ scores, long pstride) {
    const long p = blockIdx.x >> 11;
    float* pp = scores + p * pstride + ((long)(blockIdx.x & 2047) << 11);
    const int t = threadIdx.x;
    float4 f0 = *(const float4*)(pp + (t << 2));
    float4 f1 = *(const float4*)(pp + 1024 + (t << 2));
    float mx = fmaxf(fmaxf(fmaxf(f0.x, f0.y), fmaxf(f0.z, f0.w)),
                     fmaxf(fmaxf(f1.x, f1.y), fmaxf(f1.z, f1.w)));
#pragma unroll
    for (int o = 1; o < 64; o <<= 1) mx = fmaxf(mx, __shfl_xor(mx, o));
    __shared__ float red[4];
    if ((t & 63) == 0) red[t >> 6] = mx;
    __syncthreads();
    mx = fmaxf(fmaxf(red[0], red[1]), fmaxf(red[2], red[3]));
    float e0 = expf(f0.x - mx), e1 = expf(f0.y - mx), e2 = expf(f0.z - mx), e3 = expf(f0.w - mx);
    float e4 = expf(f1.x - mx), e5 = expf(f1.y - mx), e6 = expf(f1.z - mx), e7 = expf(f1.w - mx);
    float s = ((e0 + e1) + (e2 + e3)) + ((e4 + e5) + (e6 + e7));
#pragma unroll
    for (int o = 1; o < 64; o <<= 1) s += __shfl_xor(s, o);
    __syncthreads();
    if ((t & 63) == 0) red[t >> 6] = s;
    __syncthreads();
    const float inv = 1.0f / ((red[0] + red[1]) + (red[2] + red[3]));
    e0 *= inv; e1 *= inv; e2 *= inv; e3 *= inv; e4 *= inv; e5 *= inv; e6 *= inv; e7 *= inv;
    u16* hi = (u16*)pp;
    u16* lo = hi + 2048;
    u16 h0 = f2bf(e0), h1 = f2bf(e1), h2 = f2bf(e2), h3 = f2bf(e3);
    u16 h4 = f2bf(e4), h5 = f2bf(e5), h6 = f2bf(e6), h7 = f2bf(e7);
    u16x4 H0 = {h0, h1, h2, h3}, H1 = {h4, h5, h6, h7};
    u16x4 L0 = {f2bf(e0 - bf2f(h0)), f2bf(e1 - bf2f(h1)), f2bf(e2 - bf2f(h2)), f2bf(e3 - bf2f(h3))};
    u16x4 L1 = {f2bf(e4 - bf2f(h4)), f2bf(e5 - bf2f(h5)), f2bf(e6 - bf2f(h6)), f2bf(e7 - bf2f(h7))};
    *(u16x4*)(hi + (t << 2)) = H0;
    *(u16x4*)(hi + 1024 + (t << 2)) = H1;
    *(u16x4*)(lo + (t << 2)) = L0;
    *(u16x4*)(lo + 1024 + (t << 2)) = L1;
}

// ---------- transpose [2048][1024] -> [1024][2048] (u16); z = plane + 2*p ----------
__global__ void transpose_hl2(const u16* __restrict__ src_hi, u16* __restrict__ dst_hi,
                              const u16* __restrict__ src_lo, u16* __restrict__ dst_lo,
                              long sp, long dp) {
    __shared__ u16 tile[64][68];
    const long p = blockIdx.z >> 1;
    const u16* src = ((blockIdx.z & 1) ? src_lo : src_hi) + p * sp;
    u16* dst = ((blockIdx.z & 1) ? dst_lo : dst_hi) + p * dp;
    const int t0 = blockIdx.x << 6, d0 = blockIdx.y << 6;
    const int rr = threadIdx.x >> 4, cc = (threadIdx.x & 15) << 2;
#pragma unroll
    for (int it = 0; it < 4; ++it) {
        int r = (it << 4) + rr;
        u16x4 v = *(const u16x4*)(src + (long)(t0 + r) * 1024 + d0 + cc);
        tile[r][cc] = v.x; tile[r][cc + 1] = v.y; tile[r][cc + 2] = v.z; tile[r][cc + 3] = v.w;
    }
    __syncthreads();
#pragma unroll
    for (int it = 0; it < 4; ++it) {
        int r = (it << 4) + rr;
        u16x4 o;
        o.x = tile[cc][r]; o.y = tile[cc + 1][r]; o.z = tile[cc + 2][r]; o.w = tile[cc + 3][r];
        *(u16x4*)(dst + (long)(d0 + r) * 2048 + t0 + cc) = o;
    }
}

// ======================= host launcher =======================
extern "C" void kernel_launch(void* const* d_in, const int* in_sizes, int n_in,
                              void* d_out, int out_size, void* d_ws, size_t ws_size,
                              hipStream_t stream) {
    const float* x = (const float*)d_in[0];
    const float* W1 = (const float*)d_in[1];
    const float* b1 = (const float*)d_in[2];
    const float* u1 = (const float*)d_in[3];
    const float* g1 = (const float*)d_in[4];
    const float* be1 = (const float*)d_in[5];
    const float* Wq1 = (const float*)d_in[6];  const float* bq1 = (const float*)d_in[7];
    const float* Wk1 = (const float*)d_in[8];  const float* bk1 = (const float*)d_in[9];
    const float* Wv1 = (const float*)d_in[10]; const float* bv1 = (const float*)d_in[11];
    const float* W2 = (const float*)d_in[12];  const float* b2 = (const float*)d_in[13];
    const float* u2 = (const float*)d_in[14];
    const float* g2 = (const float*)d_in[15];  const float* be2 = (const float*)d_in[16];
    const float* Wq2 = (const float*)d_in[17]; const float* bq2 = (const float*)d_in[18];
    const float* Wk2 = (const float*)d_in[19]; const float* bk2 = (const float*)d_in[20];
    const float* Wv2 = (const float*)d_in[21]; const float* bv2 = (const float*)d_in[22];
    const float* W3 = (const float*)d_in[23];  const float* b3 = (const float*)d_in[24];
    const float* u3 = (const float*)d_in[25];

    // PATH1 (>=160MiB+96KB): per-batch attention, pool aliased into input region.
    // PATH2 (>=256MiB): batch-PAIR pools (2x50.33MB) after WB; FS in scores(0).
    const size_t NEED1 = 167870464ull;
    const size_t NEED2 = 268435456ull;
    if (ws_size < NEED1) {  // sentinel: error==12345 <=> this tripped
        fill_f32<<<dim3((out_size + 255) / 256), 256, 0, stream>>>((float*)d_out, 12345.0f, out_size);
        return;
    }
    const int nPair = (ws_size >= NEED2) ? 2 : 1;
    char* ws = (char*)d_ws;
    u16* R1h = (u16*)ws;                     u16* R1l = R1h + 16777216;
    u16* R2h = (u16*)(ws + 67108864);        u16* R2l = R2h + 16777216;
    u16* WBu = (u16*)(ws + 134217728);
    const long PSTRIDE = 50331648;           // pool pair stride, bytes
    char* pool2 = ws + 167772160;            // PATH2 pools (100.66MB)
    float* FS = (nPair == 2) ? (float*)pool2 : (float*)(ws + 167772160);

    u16* W1h = WBu;                 u16* W1l = WBu + 524288;
    u16* Wq1h = WBu + 1048576;      u16* Wq1l = WBu + 2097152;
    u16* Wk1h = WBu + 3145728;      u16* Wk1l = WBu + 4194304;
    u16* Wv1h = WBu + 5242880;      u16* Wv1l = WBu + 6291456;
    u16* W2h = WBu + 7340032;       u16* W2l = WBu + 8388608;
    u16* Wq2h = WBu + 9437184;      u16* Wq2l = WBu + 10485760;
    u16* Wk2h = WBu + 11534336;     u16* Wk2l = WBu + 12582912;
    u16* Wv2h = WBu + 13631488;     u16* Wv2l = WBu + 14680064;
    u16* W3h = WBu + 15728640;      u16* W3l = WBu + 16252928;

    // FS layout (floats): vpart[16*1024] | vn[1024] | rowdot[1024] | sigs | mean | rstd
    float* vpart = FS;
    float* vn = FS + 16384;
    float* rowdot = FS + 17408;
    float* sig1 = FS + 18432; float* sig2 = FS + 18433; float* sig3 = FS + 18434;
    float* mean = FS + 19456; float* rstd = FS + 21504;   // ends at 23552 floats < 96KB

    auto split = [&](const float* src, const float* sg, u16* hi, u16* lo, int nElem) {
        split_hl<<<dim3(nElem / 1024), 256, 0, stream>>>(src, sg, hi, lo, nElem / 4);
    };
    auto spec = [&](const float* W, const float* u, int N, int Kd, float* sg) {
        sn_col_part<<<dim3(Kd / 256, 16), 256, 0, stream>>>(W, u, N, Kd, vpart);
        sn_norm16<<<dim3(1), 1024, 0, stream>>>(vpart, Kd, vn);
        sn_dot<<<dim3(N / 4), 256, 0, stream>>>(W, vn, u, N, Kd, rowdot);
        sn_sig<<<dim3(1), 1024, 0, stream>>>(rowdot, N, sg);
    };

    // ---- weight prep ----
    u16* xh = R2h;  u16* xl = R2h + 8388608;   // x staged in R2 (dead after lin1)
    split(x, nullptr, xh, xl, 8388608);
    spec(W1, u1, 1024, 512, sig1);  split(W1, sig1, W1h, W1l, 524288);
    spec(W2, u2, 1024, 1024, sig2); split(W2, sig2, W2h, W2l, 1048576);
    spec(W3, u3, 512, 1024, sig3);  split(W3, sig3, W3h, W3l, 524288);
    SJ6 sj;
    sj.j[0] = {Wq1, Wq1h, Wq1l};
    sj.j[1] = {Wk1, Wk1h, Wk1l};
    sj.j[2] = {Wv1, Wv1h, Wv1l};
    sj.j[3] = {Wq2, Wq2h, Wq2l};
    sj.j[4] = {Wk2, Wk2h, Wk2l};
    sj.j[5] = {Wv2, Wv2h, Wv2l};
    split_hl6<<<dim3(1024, 6), 256, 0, stream>>>(sj, 262144);

    // full layer: X=(inh,inl); Y=(Yh,Yl); P = pool(0) base
    auto full_layer = [&](const u16* inh, const u16* inl, int Kin,
                          u16* Yh, u16* Yl, char* P,
                          const u16* Wh, const u16* Wl, const float* bl,
                          const float* g, const float* be,
                          const u16* Wqh, const u16* Wql, const float* bq,
                          const u16* Wkh, const u16* Wkl, const float* bk,
                          const u16* Wvh, const u16* Wvl, const float* bv) {
        gemm_hl<1><<<dim3(128, 8, 1), 256, 0, stream>>>(
            inh, inl, Kin, 0, Wh, Wl, Kin, 0, Kin, bl, nullptr, Yh, Yl, 1024, 0);
        bn_stats_hl<<<dim3(2048), 256, 0, stream>>>(Yh, Yl, mean, rstd);
        bn_apply_hl<<<dim3(16384), 256, 0, stream>>>(Yh, Yl, mean, rstd, g, be);
        // pool(0) interior
        float* s0 = (float*)P;
        u16* qh = (u16*)(P + 16777216); u16* ql = (u16*)(P + 20971520);
        u16* kh = (u16*)(P + 25165824); u16* kl = (u16*)(P + 29360128);
        u16* vh = (u16*)(P + 33554432); u16* vl = (u16*)(P + 37748736);
        u16* vth = (u16*)(P + 41943040); u16* vtl = (u16*)(P + 46137344);
        const long sPu = (nPair == 2) ? PSTRIDE / 2 : 0;   // pool stride, u16
        const long sPf = (nPair == 2) ? PSTRIDE / 4 : 0;   // pool stride, f32
        QKVA Q;
        Q.Bh[0] = Wqh; Q.Bl[0] = Wql; Q.bi[0] = bq; Q.Ch[0] = qh; Q.Cl[0] = ql;
        Q.Bh[1] = Wkh; Q.Bl[1] = Wkl; Q.bi[1] = bk; Q.Ch[1] = kh; Q.Cl[1] = kl;
        Q.Bh[2] = Wvh; Q.Bl[2] = Wvl; Q.bi[2] = bv; Q.Ch[2] = vh; Q.Cl[2] = vl;
        for (int b = 0; b < 8; b += nPair) {
            const long bo = (long)b * 2097152;
            gemm_qkv<<<dim3(16, 8, 3 * nPair), 256, 0, stream>>>(
                Yh + bo, Yl + bo, 1024, 2097152, Q, sPu, 1024);
            transpose_hl2<<<dim3(32, 16, 2 * nPair), 256, 0, stream>>>(
                vh, vth, vl, vtl, sPu, sPu);
            gemm_hl<0><<<dim3(16, 16, nPair), 256, 0, stream>>>(
                qh, ql, 1024, sPu, kh, kl, 1024, sPu,
                1024, nullptr, s0, nullptr, nullptr, 2048, sPf);
            softmax_hl<<<dim3(2048 * nPair), 256, 0, stream>>>(s0, sPf);
            gemm_hl<1><<<dim3(16, 8, nPair), 256, 0, stream>>>(
                (const u16*)s0, (const u16*)s0 + 2048, 4096, sPu, vth, vtl, 2048, sPu,
                2048, nullptr, nullptr, Yh + bo, Yl + bo, 1024, 2097152);
        }
    };

    // PATH1: pool aliases the layer-input region (dead by attention time).
    char* P_l1 = (nPair == 2) ? pool2 : (char*)R2h;
    char* P_l2 = (nPair == 2) ? pool2 : (char*)R1h;

    // ---- layer 1: X=R2 (x), Y=R1 ----
    full_layer(xh, xl, 512, R1h, R1l, P_l1,
               W1h, W1l, b1, g1, be1,
               Wq1h, Wq1l, bq1, Wk1h, Wk1l, bk1, Wv1h, Wv1l, bv1);
    // ---- layer 2: X=R1 (o1), Y=R2 ----
    full_layer(R1h, R1l, 1024, R2h, R2l, P_l2,
               W2h, W2l, b2, g2, be2,
               Wq2h, Wq2l, bq2, Wk2h, Wk2l, bk2, Wv2h, Wv2l, bv2);
    // ---- final linear: o2 (R2) @ W3sn^T -> d_out fp32 ----
    gemm_hl<0><<<dim3(128, 4, 1), 256, 0, stream>>>(
        R2h, R2l, 1024, 0, W3h, W3l, 1024, 0, 1024, b3,
        (float*)d_out, nullptr, nullptr, 512, 0);
}